// Round 8
// baseline (96.201 us; speedup 1.0000x reference)
//
#include <hip/hip_runtime.h>
#include <hip/hip_bf16.h>
#include <cstdint>

#define NV 64
#define NH 128
#define NB 16384
#define NCHUNK 37   // 8 diag + 28 off-diag (I<J) + 1 order-1; 64 k each

typedef __bf16 bf16x8_t __attribute__((ext_vector_type(8)));
typedef float f32x16_t __attribute__((ext_vector_type(16)));
typedef float f32x2_t __attribute__((ext_vector_type(2)));
typedef uint32_t u32x4_t __attribute__((ext_vector_type(4)));
typedef uint32_t u32x2_t __attribute__((ext_vector_type(2)));

__device__ __forceinline__ uint32_t bf16_rne(float f) {
  uint32_t u = __float_as_uint(f);
  return (u + 0x7fffu + ((u >> 16) & 1u)) >> 16;
}

// ---------------------------------------------------------------------------
// Pre-pass: bf16 B' frags in mfma_32x32x16 B-layout, symmetrized triangle.
// Frag fi = (c*4+kk)*4 + fh2 is 1 KB: lane l holds B'[h = fh2*32 + (l&31)]
//   [slot = kk*16 + (l>>5)*8 + t], bytes [l*16, l*16+16).
// c<8 diag (I=J=c):  B' = 0.5*W2[h, I8+a, I8+b]       (a=slot>>3, b=slot&7)
// 8<=c<36 (I<J):     B' = 0.5*(W2[h,i,j] + W2[h,j,i])
// c=36 order-1:      B' = W1[slot, h]
// Block per h: W2[h] (16 KB) staged in LDS once, all reads from LDS.
// ---------------------------------------------------------------------------
__global__ void cvt_kernel(const float* __restrict__ w1f,
                           const float* __restrict__ w2f,
                           uint8_t* __restrict__ frag) {
  __shared__ float W[4096];
  __shared__ float w1c[64];
  const int tid = threadIdx.x;
  const int h = blockIdx.x;
  {
    const float* src = w2f + (size_t)h * 4096;
#pragma unroll
    for (int u = 0; u < 4; ++u)
      *(float4*)(&W[u * 1024 + tid * 4]) =
          *(const float4*)(src + u * 1024 + tid * 4);
  }
  if (tid < 64) w1c[tid] = w1f[tid * 128 + h];
  __syncthreads();
  const int fh2 = h >> 5, hl = h & 31;
  for (int idx = tid; idx < 296; idx += 256) {  // idx = c*8 + kk*2 + lh
    int c = idx >> 3, kk = (idx >> 1) & 3, lh = idx & 1;
    int a = kk * 2 + lh;   // slot>>3 for this task's 8 slots
    float v[8];
    if (c < 8) {
      int ib = (c * 8 + a) * 64 + c * 8;
#pragma unroll
      for (int t = 0; t < 8; ++t) v[t] = 0.5f * W[ib + t];
    } else if (c < 36) {
      int o = c - 8, I = 0;
      while (o >= 7 - I) { o -= 7 - I; ++I; }
      int J = I + 1 + o;
      int i = I * 8 + a;
#pragma unroll
      for (int t = 0; t < 8; ++t) {
        int j = J * 8 + t;
        v[t] = 0.5f * (W[i * 64 + j] + W[j * 64 + i]);
      }
    } else {
      int sb = kk * 16 + lh * 8;
#pragma unroll
      for (int t = 0; t < 8; ++t) v[t] = w1c[sb + t];
    }
    uint4 o4;
    o4.x = (bf16_rne(v[1]) << 16) | bf16_rne(v[0]);
    o4.y = (bf16_rne(v[3]) << 16) | bf16_rne(v[2]);
    o4.z = (bf16_rne(v[5]) << 16) | bf16_rne(v[4]);
    o4.w = (bf16_rne(v[7]) << 16) | bf16_rne(v[6]);
    *(uint4*)(frag + ((size_t)((c * 4 + kk) * 4 + fh2) << 10) +
              ((lh * 32 + hl) << 4)) = o4;
  }
}

// ---------------------------------------------------------------------------
// Main: P[ks, m, h] = partial sum over this ks's chunks of A[m,k]*B'[h,k].
// Wave = 32m x 32h via mfma_f32_32x32x16_bf16; lane owns ONE x row (m=lane&31)
// as 32 f32x2 regs. A on the fly: s = x[I8 + kk*2 + lh] (1 cndmask),
// afrag = s * x[J-group] (4 pk_mul + 4 perm). No LDS, no barriers, depth-1
// register prefetch of the 4 B-frags. Block 512 = 2 wm x 4 hq; grid (256,2).
// ---------------------------------------------------------------------------
__device__ __forceinline__ uint32_t pack2(f32x2_t pr) {
  u32x2_t u = __builtin_bit_cast(u32x2_t, pr);
  return __builtin_amdgcn_perm(u[1], u[0], 0x07060302);  // hi halves (trunc)
}

template <int C0, int C1>
__device__ __forceinline__ void kloop(const uint8_t* pw, const f32x2_t* xb,
                                      int lh, f32x16_t& acc, bf16x8_t* bn) {
  constexpr int CI[36] = {0,1,2,3,4,5,6,7, 0,0,0,0,0,0,0, 1,1,1,1,1,1,
                          2,2,2,2,2, 3,3,3,3, 4,4,4, 5,5, 6};
  constexpr int CJ[36] = {0,1,2,3,4,5,6,7, 1,2,3,4,5,6,7, 2,3,4,5,6,7,
                          3,4,5,6,7, 4,5,6,7, 5,6,7, 6,7, 7};
#pragma unroll
  for (int c = C0; c < C1; ++c) {
    bf16x8_t bc[4];
#pragma unroll
    for (int kk = 0; kk < 4; ++kk) bc[kk] = bn[kk];
    const uint8_t* pn = pw + (size_t)(c + 1) * 16384;  // prefetch chunk c+1
#pragma unroll
    for (int kk = 0; kk < 4; ++kk)
      bn[kk] = *(const bf16x8_t*)(pn + kk * 4096);
    const int I = CI[c], J = CJ[c];
#pragma unroll
    for (int kk = 0; kk < 4; ++kk) {
      f32x2_t sp = xb[I * 4 + kk];
      float s = lh ? sp.y : sp.x;           // v_cndmask on lane-half
      f32x2_t s2 = {s, s};
      u32x4_t adv;
#pragma unroll
      for (int tt = 0; tt < 4; ++tt)
        adv[tt] = pack2(s2 * xb[J * 4 + tt]);  // v_pk_mul_f32 + perm
      acc = __builtin_amdgcn_mfma_f32_32x32x16_bf16(
          __builtin_bit_cast(bf16x8_t, adv), bc[kk], acc, 0, 0, 0);
    }
  }
}

__launch_bounds__(512, 4)
__global__ void rbm_main(const float* __restrict__ xg,
                         const uint8_t* __restrict__ frag,
                         float* __restrict__ P) {
  const int tid = threadIdx.x;
  const int wv = tid >> 6;
  const int wm = wv & 1;     // m half (32 rows)
  const int hq = wv >> 1;    // h quarter (32 cols)
  const int lane = tid & 63;
  const int l31 = lane & 31;
  const int lh = lane >> 5;
  const int mblk = blockIdx.x * 64;
  const int ks = blockIdx.y;

  // lane's x row -> 32 f32x2 registers (global origin: no LDS remat)
  f32x2_t xb[32];
  {
    const float* p = xg + (size_t)(mblk + wm * 32 + l31) * NV;
#pragma unroll
    for (int g = 0; g < 16; ++g) {
      float4 v = *(const float4*)(p + g * 4);
      xb[g * 2] = f32x2_t{v.x, v.y};
      xb[g * 2 + 1] = f32x2_t{v.z, v.w};
    }
  }

  const uint8_t* pw = frag + hq * 1024 + (size_t)lane * 16;
  f32x16_t acc = (f32x16_t)0.0f;
  bf16x8_t bn[4];
  {
    const uint8_t* p0 = pw + (size_t)(ks ? 18 : 0) * 16384;
#pragma unroll
    for (int kk = 0; kk < 4; ++kk)
      bn[kk] = *(const bf16x8_t*)(p0 + kk * 4096);
  }

  if (ks == 0) {
    kloop<0, 18>(pw, xb, lh, acc, bn);
  } else {
    kloop<18, 36>(pw, xb, lh, acc, bn);
    // tail chunk 36 (order-1): A = x directly; bn holds chunk-36 frags
#pragma unroll
    for (int kk = 0; kk < 4; ++kk) {
      u32x4_t adv;
#pragma unroll
      for (int tt = 0; tt < 4; ++tt) {
        f32x2_t v = lh ? xb[kk * 8 + 4 + tt] : xb[kk * 8 + tt];
        adv[tt] = pack2(v);
      }
      acc = __builtin_amdgcn_mfma_f32_32x32x16_bf16(
          __builtin_bit_cast(bf16x8_t, adv), bn[kk], acc, 0, 0, 0);
    }
  }

  // C/D 32x32 layout (m74/m101): col=lane&31 (h), row=(r&3)+8*(r>>2)+4*lh (m)
  float* pp = P + ((size_t)(ks * NB + mblk + wm * 32)) * NH + hq * 32 + l31;
#pragma unroll
  for (int r = 0; r < 16; ++r) {
    int mloc = (r & 3) + 8 * (r >> 2) + 4 * lh;
    pp[(size_t)mloc * NH] = acc[r];
  }
}

// ---------------------------------------------------------------------------
// Reduce: psi[m] = prod_h cos(P0[m,h] + P1[m,h] + bias[h]).
// Wave handles 4 m; lanes own 2 h each; width-64 product butterfly.
// ---------------------------------------------------------------------------
__global__ void reduce_kernel(const float* __restrict__ P,
                              const float* __restrict__ biasg,
                              float* __restrict__ outg) {
  const int tid = threadIdx.x;
  const int wv = tid >> 6;
  const int lane = tid & 63;
  const int m0 = blockIdx.x * 16 + wv * 4;
  const float b0 = biasg[lane], b1 = biasg[64 + lane];
  const float INV2PI = 0.15915494309189535f;
#pragma unroll
  for (int u = 0; u < 4; ++u) {
    const int m = m0 + u;
    const float* p0 = P + (size_t)m * NH;
    const float* p1 = P + (size_t)(NB + m) * NH;
    float a0 = p0[lane] + p1[lane] + b0;
    float a1 = p0[64 + lane] + p1[64 + lane] + b1;
    float pr = __builtin_amdgcn_cosf(a0 * INV2PI) *
               __builtin_amdgcn_cosf(a1 * INV2PI);
#pragma unroll
    for (int ofs = 1; ofs < 64; ofs <<= 1)
      pr *= __shfl_xor(pr, ofs, 64);
    if (lane == 0) outg[m] = pr;
  }
}

extern "C" void kernel_launch(void* const* d_in, const int* in_sizes, int n_in,
                              void* d_out, int out_size, void* d_ws, size_t ws_size,
                              hipStream_t stream) {
  const float* x   = (const float*)d_in[0];
  const float* w1f = (const float*)d_in[1];
  const float* w2f = (const float*)d_in[2];
  const float* hb  = (const float*)d_in[3];
  float* out = (float*)d_out;
  uint8_t* frag = (uint8_t*)d_ws;                       // 592 KB bf16 frags
  float* P = (float*)((uint8_t*)d_ws + (1 << 20));      // 16 MB partials
  (void)in_sizes; (void)n_in; (void)out_size; (void)ws_size;

  cvt_kernel<<<128, 256, 0, stream>>>(w1f, w2f, frag);
  rbm_main<<<dim3(NB / 64, 2), 512, 0, stream>>>(x, frag, P);
  reduce_kernel<<<NB / 16, 256, 0, stream>>>(P, hb, out);
}